// Round 18
// baseline (134.441 us; speedup 1.0000x reference)
//
#include <hip/hip_runtime.h>
#include <hip/hip_bf16.h>
#include <cstdio>

typedef __hip_bfloat16 bf16;
typedef __bf16 bf16x8 __attribute__((ext_vector_type(8)));
typedef float f32x4 __attribute__((ext_vector_type(4)));

#define B_DIM 4
#define T_DIM 4096
#define D_DIM 1024
#define NC 64   // chunks along T
#define LC 64   // chunk length; NC*LC == T_DIM

#define M_DIM (B_DIM * T_DIM)  // 16384
#define BM 256
#define BN 256
#define BK 32
#define NT (D_DIM / BK)        // 32 K-tiles
#define GM (M_DIM / BM)        // 64
#define GN (D_DIM / BN)        // 4

static __device__ __forceinline__ float bfbits2f(unsigned short u) {
  return __uint_as_float(((unsigned)u) << 16);
}
static __device__ __forceinline__ unsigned short f2bfbits(float f) {
  bf16 v = __float2bfloat16(f);
  return *reinterpret_cast<unsigned short*>(&v);
}

// ---------------------------------------------------------------- SSM pass 1
// Blocks [0, 512): per-chunk local scan with h_in = 0 over x~ = bf16(x);
// emits terminal state hfin AND the bf16 cast x16.
// Blocks [512, 640): weight cast (float4 in, ushort4 out), fused to kill
// a separate dispatch + launch gap.
__global__ __launch_bounds__(256) void ssm_pass1(
    const float* __restrict__ x, const float* __restrict__ A,
    const float* __restrict__ Bp, float* __restrict__ hfin,
    unsigned short* __restrict__ x16,
    const float* __restrict__ gw, const float* __restrict__ ow,
    unsigned short* __restrict__ gw16, unsigned short* __restrict__ ow16) {
  const int bidx = blockIdx.x;
  if (bidx >= B_DIM * NC * 2) {
    // ---- weight cast: 128 blocks x 256 thr x 32 elems per array
    const int t = (bidx - B_DIM * NC * 2) * 256 + threadIdx.x;
#pragma unroll
    for (int j = 0; j < 8; ++j) {
      const int e = t * 32 + j * 4;
      const float4 g = *reinterpret_cast<const float4*>(gw + e);
      const float4 o = *reinterpret_cast<const float4*>(ow + e);
      *reinterpret_cast<ushort4*>(gw16 + e) = make_ushort4(
          f2bfbits(g.x), f2bfbits(g.y), f2bfbits(g.z), f2bfbits(g.w));
      *reinterpret_cast<ushort4*>(ow16 + e) = make_ushort4(
          f2bfbits(o.x), f2bfbits(o.y), f2bfbits(o.z), f2bfbits(o.w));
    }
    return;
  }
  const int tid  = threadIdx.x;
  const int half = bidx & 1;                  // D/512 = 2
  const int c    = (bidx >> 1) & (NC - 1);
  const int b    = bidx >> 7;                 // / (2*NC)
  const int d0   = half * 512 + tid * 2;
  const float a0 = A[d0], a1 = A[d0 + 1];
  const float bp0 = Bp[d0], bp1 = Bp[d0 + 1];
  const size_t base = (size_t)(b * T_DIM + c * LC) * D_DIM + d0;
  float h0 = 0.f, h1 = 0.f;
#pragma unroll 4
  for (int i = 0; i < LC; ++i) {
    const size_t o = base + (size_t)i * D_DIM;
    const float2 xv = *reinterpret_cast<const float2*>(x + o);
    const unsigned short u0 = f2bfbits(xv.x), u1 = f2bfbits(xv.y);
    const float f0 = bfbits2f(u0), f1 = bfbits2f(u1);  // scan the ROUNDED x
    h0 = fmaf(a0, h0, bp0 * f0);
    h1 = fmaf(a1, h1, bp1 * f1);
    *reinterpret_cast<ushort2*>(x16 + o) = make_ushort2(u0, u1);
  }
  const int ho = (b * NC + c) * D_DIM + d0;
  hfin[ho] = h0;
  hfin[ho + 1] = h1;
}

// ---------------------------------------------------------------- GEMM 256x256
// GEMM core = R9 (best of 6 structural variants: 48.7us/710TF): 256x256
// tile, BK=32, 8 waves (2Mx4N), ring-4 LDS, prefetch distance 3, counted
// vmcnt (T4), T2 XOR swizzle both-sides (0 conflicts), T5 setprio,
// mid-tile single barrier with split MFMA halves, XCD-chunked swizzle.
// R18 (GATE only): pass2 AND pass3 fused into the prologue (serial rec,
// R16 form — R17's K-loop pipelining measured 4us slower and is reverted):
//  - in-block pass2: hin(bb, cbase+ck, d) computed by replaying pass2's
//    exact scan h = fmaf(aL, h, hfin[c]) for c in [0, cbase+ck), with the
//    same aL = A[d] six-squarings -> bit-identical to the old kernel.
//    ck is wave-uniform (no divergence); hfin is 1 MB, L2-resident.
//  - rec: 2 chains/thread x 64 steps over x16, emits ssm16; all loads/
//    stores drained by the pre-loop vmcnt(0)+barrier (R16-proven); own
//    epilogue re-reads ssm16 (same block -> coherent).
// Ledger: after the pre-loop drain, outstanding = 0; steady vmcnt(8)
// waits S(t+1); tail vmcnt(4)/vmcnt(0) as R9.
template <bool GATE>
__global__ __launch_bounds__(512) void gemm256(
    const bf16* __restrict__ Xm, const bf16* __restrict__ Wm,
    const float* __restrict__ bias, const bf16* __restrict__ ssm,
    bf16* __restrict__ Ybf, float* __restrict__ Yf,
    const unsigned short* __restrict__ x16s, const float* __restrict__ Ap,
    const float* __restrict__ Bpp, const float* __restrict__ Cpp,
    const float* __restrict__ hfinp) {
  __shared__ __align__(16) short LDS[4][16384];  // 4 x 32 KiB = 128 KiB

  const int tid  = threadIdx.x;
  const int lane = tid & 63;
  const int wave = tid >> 6;
  const int wm = wave >> 2;           // 0..1
  const int wn = wave & 3;            // 0..3
  const int l15 = lane & 15;
  const int sA = ((lane >> 4) ^ ((l15 >> 1) & 3)) << 3;  // shorts

  const int bid = blockIdx.x;
  const int swz = (bid & 7) * (GM * GN / 8) + (bid >> 3);
  const int m0 = (swz >> 2) * BM;
  const int n0 = (swz & 3) * BN;

  const int row0 = tid >> 2;
  const int c0   = (tid & 3) ^ ((row0 >> 1) & 3);
  const size_t offA0 = (size_t)(m0 + row0) * D_DIM + c0 * 8;
  const size_t offB0 = (size_t)(n0 + row0) * D_DIM + c0 * 8;

  auto gll = [](const bf16* g, short* l) {
    __builtin_amdgcn_global_load_lds(
        (const __attribute__((address_space(1))) void*)g,
        (__attribute__((address_space(3))) void*)l, 16, 0, 0);
  };
  auto STAGE = [&](int buf, int kt) {
    const size_t ko = (size_t)kt * BK;
    short* b0 = &LDS[buf][0] + wave * 512;
    gll(Xm + offA0 + ko,               b0);
    gll(Xm + offA0 + 128 * D_DIM + ko, b0 + 4096);
    gll(Wm + offB0 + ko,               b0 + 8192);
    gll(Wm + offB0 + 128 * D_DIM + ko, b0 + 12288);
  };

  f32x4 acc[8][4] = {};

  // prologue: prime tiles 0,1,2 (12 loads/wave in flight)
  STAGE(0, 0);
  STAGE(1, 1);
  STAGE(2, 2);

  if (GATE) {
    // ---- fused pass2 + pass3 (runs while the first GEMM tiles stream in)
    unsigned short* ssms = (unsigned short*)ssm;
    const int bb_   = m0 >> 12;            // batch index (BM=256 | 4096)
    const int cbase = (m0 & 4095) >> 6;    // first 64-step chunk
#pragma unroll
    for (int p = 0; p < 2; ++p) {
      const int idx = p * 512 + tid;
      const int ch  = idx & 255;
      const int ck  = idx >> 8;            // 0..3 (wave-uniform)
      const int d   = n0 + ch;
      const float a = Ap[d], bp = Bpp[d], cp = Cpp[d];
      // in-block pass2: aL = a^64 (same 6 squarings), then replay the scan
      float aL = a;
#pragma unroll
      for (int s = 0; s < 6; ++s) aL *= aL;
      float h = 0.f;
      const int ce = cbase + ck;
      for (int c = 0; c < ce; ++c)
        h = fmaf(aL, h, hfinp[(bb_ * NC + c) * D_DIM + d]);
      // pass3 replay: 64 recurrence steps, emit ssm16
      size_t o = (size_t)(m0 + ck * 64) * D_DIM + d;
#pragma unroll 8
      for (int i = 0; i < LC; ++i, o += D_DIM) {
        h = fmaf(a, h, bp * bfbits2f(x16s[o]));
        ssms[o] = f2bfbits(cp * h);
      }
    }
  }

  // drain: rec loads/stores + prologue gll all complete -> ledger starts
  // at 0 outstanding; also publishes ssm16 stores for the epilogue.
  asm volatile("s_waitcnt vmcnt(0)" ::: "memory");
  __builtin_amdgcn_s_barrier();

#define KTILE_BODY(T_, VMSTR, DO_STAGE, DO_BAR)                             \
  {                                                                         \
    const short* bb = &LDS[(T_) & 3][0];                                    \
    bf16x8 a[8], b[4];                                                      \
    _Pragma("unroll")                                                       \
    for (int i = 0; i < 4; ++i)                                             \
      a[i] = *(const bf16x8*)(bb + (wm * 128 + i * 16 + l15) * BK + sA);    \
    _Pragma("unroll")                                                       \
    for (int j = 0; j < 4; ++j)                                             \
      b[j] = *(const bf16x8*)(bb + 8192 + (wn * 64 + j * 16 + l15) * BK + sA); \
    _Pragma("unroll")                                                       \
    for (int i = 4; i < 8; ++i)                                             \
      a[i] = *(const bf16x8*)(bb + (wm * 128 + i * 16 + l15) * BK + sA);    \
    if (DO_STAGE) STAGE(((T_) + 3) & 3, (T_) + 3);                          \
    __builtin_amdgcn_s_setprio(1);                                          \
    _Pragma("unroll")                                                       \
    for (int i = 0; i < 4; ++i)                                             \
      _Pragma("unroll")                                                     \
      for (int j = 0; j < 4; ++j)                                           \
        acc[i][j] =                                                         \
            __builtin_amdgcn_mfma_f32_16x16x32_bf16(a[i], b[j], acc[i][j], 0, 0, 0); \
    __builtin_amdgcn_s_setprio(0);                                          \
    if (DO_BAR) {                                                           \
      asm volatile("s_waitcnt " VMSTR ::: "memory");                        \
      __builtin_amdgcn_s_barrier();                                         \
    }                                                                       \
    __builtin_amdgcn_s_setprio(1);                                          \
    _Pragma("unroll")                                                       \
    for (int i = 4; i < 8; ++i)                                             \
      _Pragma("unroll")                                                     \
      for (int j = 0; j < 4; ++j)                                           \
        acc[i][j] =                                                         \
            __builtin_amdgcn_mfma_f32_16x16x32_bf16(a[i], b[j], acc[i][j], 0, 0, 0); \
    __builtin_amdgcn_s_setprio(0);                                          \
  }

  for (int t = 0; t < NT - 3; ++t)        // t = 0..28: stage t+3 = 3..31
    KTILE_BODY(t, "vmcnt(8)", true, true);
  KTILE_BODY(NT - 3, "vmcnt(4)", false, true);  // ensure tile NT-2 landed
  KTILE_BODY(NT - 2, "vmcnt(0)", false, true);  // ensure tile NT-1 landed
  KTILE_BODY(NT - 1, "vmcnt(0)", false, false); // last tile: no barrier
#undef KTILE_BODY

  // ---- epilogue: C/D layout col = lane&15, row = (lane>>4)*4 + v  [m89/m91]
#pragma unroll
  for (int i = 0; i < 8; ++i) {
#pragma unroll
    for (int j = 0; j < 4; ++j) {
      const int col = n0 + wn * 64 + j * 16 + l15;
      const float bv = bias[col];
#pragma unroll
      for (int v = 0; v < 4; ++v) {
        const int row = m0 + wm * 128 + i * 16 + (lane >> 4) * 4 + v;
        const size_t o = (size_t)row * D_DIM + col;
        const float val = acc[i][j][v] + bv;
        if (GATE) {
          const float g = 1.f / (1.f + expf(-val));
          Ybf[o] = __float2bfloat16(g * __bfloat162float(ssm[o]));
        } else {
          Yf[o] = val;
        }
      }
    }
  }
}

// ---------------------------------------------------------------- launch
extern "C" void kernel_launch(void* const* d_in, const int* in_sizes, int n_in,
                              void* d_out, int out_size, void* d_ws, size_t ws_size,
                              hipStream_t stream) {
  const float* x  = (const float*)d_in[0];
  const float* A  = (const float*)d_in[1];
  const float* Bp = (const float*)d_in[2];
  const float* Cp = (const float*)d_in[3];
  const float* gw = (const float*)d_in[4];
  const float* gb = (const float*)d_in[5];
  const float* ow = (const float*)d_in[6];
  const float* ob = (const float*)d_in[7];
  float* out = (float*)d_out;

  // workspace layout (bytes)
  const size_t NEED = 73400320;
  if (ws_size < NEED) {
    fprintf(stderr, "kernel_launch: ws_size %zu < needed %zu\n", ws_size, NEED);
    return;
  }
  char* ws = (char*)d_ws;
  bf16*  x16   = (bf16*)(ws);                   // 33,554,432 B : x cast to bf16
  bf16*  ssm16 = (bf16*)(ws + 33554432);        // 33,554,432 B : ssm, then y in-place
  bf16*  gw16  = (bf16*)(ws + 67108864);        //  2,097,152 B
  bf16*  ow16  = (bf16*)(ws + 69206016);        //  2,097,152 B
  float* hfin  = (float*)(ws + 71303168);       //  1,048,576 B
  // (remaining 1 MB unused)

  // pass1 + fused weight cast: 512 ssm blocks + 128 cast blocks
  ssm_pass1<<<B_DIM * NC * 2 + 128, 256, 0, stream>>>(
      x, A, Bp, hfin, (unsigned short*)x16, gw, ow,
      (unsigned short*)gw16, (unsigned short*)ow16);

  // gate GEMM with fused pass2 + pass3 (serial rec), then
  // y = sigmoid(x@gw^T + gb) * ssm  (written in-place over ssm16)
  gemm256<true><<<GM * GN, 512, 0, stream>>>(
      x16, gw16, gb, ssm16, ssm16, nullptr,
      (const unsigned short*)x16, A, Bp, Cp, hfin);
  // out GEMM: out = y@ow^T + ob  (fp32)
  gemm256<false><<<GM * GN, 512, 0, stream>>>(
      ssm16, ow16, ob, nullptr, nullptr, out,
      nullptr, nullptr, nullptr, nullptr, nullptr);
}

// Round 19
// 123.497 us; speedup vs baseline: 1.0886x; 1.0886x over previous
//
#include <hip/hip_runtime.h>
#include <hip/hip_bf16.h>
#include <cstdio>

typedef __hip_bfloat16 bf16;
typedef __bf16 bf16x8 __attribute__((ext_vector_type(8)));
typedef float f32x4 __attribute__((ext_vector_type(4)));

#define B_DIM 4
#define T_DIM 4096
#define D_DIM 1024
#define NC 64   // chunks along T
#define LC 64   // chunk length; NC*LC == T_DIM

#define M_DIM (B_DIM * T_DIM)  // 16384
#define BM 256
#define BN 256
#define BK 32
#define NT (D_DIM / BK)        // 32 K-tiles
#define GM (M_DIM / BM)        // 64
#define GN (D_DIM / BN)        // 4

static __device__ __forceinline__ float bfbits2f(unsigned short u) {
  return __uint_as_float(((unsigned)u) << 16);
}
static __device__ __forceinline__ unsigned short f2bfbits(float f) {
  bf16 v = __float2bfloat16(f);
  return *reinterpret_cast<unsigned short*>(&v);
}

// ---------------------------------------------------------------- SSM pass 1
// Blocks [0, 512): per-chunk local scan with h_in = 0 over x~ = bf16(x);
// emits terminal state hfin AND the bf16 cast x16.
// Blocks [512, 640): weight cast (float4 in, ushort4 out) — independent
// blocks, no serial chain; fused only to kill a dispatch + launch gap.
__global__ __launch_bounds__(256) void ssm_pass1(
    const float* __restrict__ x, const float* __restrict__ A,
    const float* __restrict__ Bp, float* __restrict__ hfin,
    unsigned short* __restrict__ x16,
    const float* __restrict__ gw, const float* __restrict__ ow,
    unsigned short* __restrict__ gw16, unsigned short* __restrict__ ow16) {
  const int bidx = blockIdx.x;
  if (bidx >= B_DIM * NC * 2) {
    const int t = (bidx - B_DIM * NC * 2) * 256 + threadIdx.x;
#pragma unroll
    for (int j = 0; j < 8; ++j) {
      const int e = t * 32 + j * 4;
      const float4 g = *reinterpret_cast<const float4*>(gw + e);
      const float4 o = *reinterpret_cast<const float4*>(ow + e);
      *reinterpret_cast<ushort4*>(gw16 + e) = make_ushort4(
          f2bfbits(g.x), f2bfbits(g.y), f2bfbits(g.z), f2bfbits(g.w));
      *reinterpret_cast<ushort4*>(ow16 + e) = make_ushort4(
          f2bfbits(o.x), f2bfbits(o.y), f2bfbits(o.z), f2bfbits(o.w));
    }
    return;
  }
  const int tid  = threadIdx.x;
  const int half = bidx & 1;                  // D/512 = 2
  const int c    = (bidx >> 1) & (NC - 1);
  const int b    = bidx >> 7;                 // / (2*NC)
  const int d0   = half * 512 + tid * 2;
  const float a0 = A[d0], a1 = A[d0 + 1];
  const float bp0 = Bp[d0], bp1 = Bp[d0 + 1];
  const size_t base = (size_t)(b * T_DIM + c * LC) * D_DIM + d0;
  float h0 = 0.f, h1 = 0.f;
#pragma unroll 4
  for (int i = 0; i < LC; ++i) {
    const size_t o = base + (size_t)i * D_DIM;
    const float2 xv = *reinterpret_cast<const float2*>(x + o);
    const unsigned short u0 = f2bfbits(xv.x), u1 = f2bfbits(xv.y);
    const float f0 = bfbits2f(u0), f1 = bfbits2f(u1);  // scan the ROUNDED x
    h0 = fmaf(a0, h0, bp0 * f0);
    h1 = fmaf(a1, h1, bp1 * f1);
    *reinterpret_cast<ushort2*>(x16 + o) = make_ushort2(u0, u1);
  }
  const int ho = (b * NC + c) * D_DIM + d0;
  hfin[ho] = h0;
  hfin[ho + 1] = h1;
}

// ---------------------------------------------------------------- SSM pass 2
// Separate kernel (R18's in-block fusion = 64-deep dependent L2 chain in
// the gate prologue, +17us — falsified and reverted).
__global__ __launch_bounds__(256) void ssm_pass2(
    const float* __restrict__ A, const float* __restrict__ hfin,
    float* __restrict__ hin) {
  const int idx = blockIdx.x * 256 + threadIdx.x;  // B*D = 4096
  const int d = idx & (D_DIM - 1);
  const int b = idx >> 10;
  float aL = A[d];
#pragma unroll
  for (int s = 0; s < 6; ++s) aL *= aL;  // A^64 (LC = 2^6)
  float h = 0.f;
  for (int c = 0; c < NC; ++c) {
    const int o = (b * NC + c) * D_DIM + d;
    hin[o] = h;
    h = fmaf(aL, h, hfin[o]);
  }
}

// ---------------------------------------------------------------- GEMM 256x256
// R19 = R17 exactly (best measured wall: 125.4us): GEMM core R9 (best of
// 6 structural variants) + fused ssm recurrence PIPELINED through the
// K-loop (16 chunks x 4 steps x 2 chains; loads at tile t into rlA/rlB by
// parity, FMAs+stores at t+2; extended vmcnt ledger counts all younger vm
// ops; rec stores drained at t30's vmcnt(0)+barrier before the epilogue
// reads ssm). T2 XOR swizzle both-sides (0 conflicts), T5 setprio,
// mid-tile barrier with split MFMA halves, XCD-chunked swizzle.
template <bool GATE>
__global__ __launch_bounds__(512) void gemm256(
    const bf16* __restrict__ Xm, const bf16* __restrict__ Wm,
    const float* __restrict__ bias, const bf16* __restrict__ ssm,
    bf16* __restrict__ Ybf, float* __restrict__ Yf,
    const unsigned short* __restrict__ x16s, const float* __restrict__ Ap,
    const float* __restrict__ Bpp, const float* __restrict__ Cpp,
    const float* __restrict__ hinp) {
  __shared__ __align__(16) short LDS[4][16384];  // 4 x 32 KiB = 128 KiB

  const int tid  = threadIdx.x;
  const int lane = tid & 63;
  const int wave = tid >> 6;
  const int wm = wave >> 2;           // 0..1
  const int wn = wave & 3;            // 0..3
  const int l15 = lane & 15;
  const int sA = ((lane >> 4) ^ ((l15 >> 1) & 3)) << 3;  // shorts

  const int bid = blockIdx.x;
  const int swz = (bid & 7) * (GM * GN / 8) + (bid >> 3);
  const int m0 = (swz >> 2) * BM;
  const int n0 = (swz & 3) * BN;

  const int row0 = tid >> 2;
  const int c0   = (tid & 3) ^ ((row0 >> 1) & 3);
  const size_t offA0 = (size_t)(m0 + row0) * D_DIM + c0 * 8;
  const size_t offB0 = (size_t)(n0 + row0) * D_DIM + c0 * 8;

  auto gll = [](const bf16* g, short* l) {
    __builtin_amdgcn_global_load_lds(
        (const __attribute__((address_space(1))) void*)g,
        (__attribute__((address_space(3))) void*)l, 16, 0, 0);
  };
  auto STAGE = [&](int buf, int kt) {
    const size_t ko = (size_t)kt * BK;
    short* b0 = &LDS[buf][0] + wave * 512;
    gll(Xm + offA0 + ko,               b0);
    gll(Xm + offA0 + 128 * D_DIM + ko, b0 + 4096);
    gll(Wm + offB0 + ko,               b0 + 8192);
    gll(Wm + offB0 + 128 * D_DIM + ko, b0 + 12288);
  };

  f32x4 acc[8][4] = {};

  // ---- rec chain state (GATE only; DCE'd otherwise).
  float ar = 0.f, bpr = 0.f, cpr = 0.f, h0 = 0.f, h1 = 0.f;
  size_t lo0 = 0, so0 = 0;
  unsigned short* ssms = (unsigned short*)ssm;
  unsigned short rlA[8], rlB[8];
  if (GATE) {
    const int ch = tid & 255;
    const int ck = tid >> 8;             // 0..1
    const int d  = n0 + ch;
    ar = Ap[d]; bpr = Bpp[d]; cpr = Cpp[d];
    const int bb_   = m0 >> 12;
    const int cbase = (m0 & 4095) >> 6;
    h0 = hinp[(bb_ * NC + cbase + ck) * D_DIM + d];
    h1 = hinp[(bb_ * NC + cbase + ck + 2) * D_DIM + d];
    lo0 = (size_t)(m0 + ck * 64) * D_DIM + d;
    so0 = lo0;
  }

  // prologue: prime tiles 0,1,2 (rec param loads are OLDER than S0).
  STAGE(0, 0);
  STAGE(1, 1);
  STAGE(2, 2);
  asm volatile("s_waitcnt vmcnt(8)" ::: "memory");
  __builtin_amdgcn_s_barrier();  // tile 0 staged for all waves

  // MODE_: 0 none, 1 load-only, 2 comp+load, 3 comp-only
#define RECBLK(RL_, MODE_)                                                  \
    if (GATE && (MODE_) >= 2) {                                             \
      _Pragma("unroll")                                                     \
      for (int s = 0; s < 4; ++s) {                                         \
        h0 = fmaf(ar, h0, bpr * bfbits2f(RL_[2 * s]));                      \
        ssms[so0 + (size_t)s * D_DIM] = f2bfbits(cpr * h0);                 \
        h1 = fmaf(ar, h1, bpr * bfbits2f(RL_[2 * s + 1]));                  \
        ssms[so0 + (size_t)(128 + s) * D_DIM] = f2bfbits(cpr * h1);         \
      }                                                                     \
      so0 += 4 * D_DIM;                                                     \
    }                                                                       \
    if (GATE && ((MODE_) == 1 || (MODE_) == 2)) {                           \
      _Pragma("unroll")                                                     \
      for (int s = 0; s < 4; ++s) {                                         \
        RL_[2 * s]     = x16s[lo0 + (size_t)s * D_DIM];                     \
        RL_[2 * s + 1] = x16s[lo0 + (size_t)(128 + s) * D_DIM];             \
      }                                                                     \
      lo0 += 4 * D_DIM;                                                     \
    }

#define KTILE_BODY(T_, VMSTR, DO_STAGE, DO_BAR, RL_, MODE_)                 \
  {                                                                         \
    const short* bb = &LDS[(T_) & 3][0];                                    \
    bf16x8 a[8], b[4];                                                      \
    _Pragma("unroll")                                                       \
    for (int i = 0; i < 4; ++i)                                             \
      a[i] = *(const bf16x8*)(bb + (wm * 128 + i * 16 + l15) * BK + sA);    \
    _Pragma("unroll")                                                       \
    for (int j = 0; j < 4; ++j)                                             \
      b[j] = *(const bf16x8*)(bb + 8192 + (wn * 64 + j * 16 + l15) * BK + sA); \
    _Pragma("unroll")                                                       \
    for (int i = 4; i < 8; ++i)                                             \
      a[i] = *(const bf16x8*)(bb + (wm * 128 + i * 16 + l15) * BK + sA);    \
    if (DO_STAGE) STAGE(((T_) + 3) & 3, (T_) + 3);                          \
    RECBLK(RL_, MODE_)                                                      \
    __builtin_amdgcn_s_setprio(1);                                          \
    _Pragma("unroll")                                                       \
    for (int i = 0; i < 4; ++i)                                             \
      _Pragma("unroll")                                                     \
      for (int j = 0; j < 4; ++j)                                           \
        acc[i][j] =                                                         \
            __builtin_amdgcn_mfma_f32_16x16x32_bf16(a[i], b[j], acc[i][j], 0, 0, 0); \
    __builtin_amdgcn_s_setprio(0);                                          \
    if (DO_BAR) {                                                           \
      asm volatile("s_waitcnt " VMSTR ::: "memory");                        \
      __builtin_amdgcn_s_barrier();                                         \
    }                                                                       \
    __builtin_amdgcn_s_setprio(1);                                          \
    _Pragma("unroll")                                                       \
    for (int i = 4; i < 8; ++i)                                             \
      _Pragma("unroll")                                                     \
      for (int j = 0; j < 4; ++j)                                           \
        acc[i][j] =                                                         \
            __builtin_amdgcn_mfma_f32_16x16x32_bf16(a[i], b[j], acc[i][j], 0, 0, 0); \
    __builtin_amdgcn_s_setprio(0);                                          \
  }

  if (GATE) {
    KTILE_BODY(0, "vmcnt(16)", true, true, rlA, 1)
    KTILE_BODY(1, "vmcnt(24)", true, true, rlB, 1)
    KTILE_BODY(2, "vmcnt(40)", true, true, rlA, 2)
    KTILE_BODY(3, "vmcnt(48)", true, true, rlB, 2)
    for (int t = 4; t <= 14; t += 2) {   // pairs (4,5)...(14,15)
      KTILE_BODY(t,     "vmcnt(56)", true, true, rlA, 2)
      KTILE_BODY(t + 1, "vmcnt(56)", true, true, rlB, 2)
    }
    KTILE_BODY(16, "vmcnt(48)", true, true, rlA, 3)
    KTILE_BODY(17, "vmcnt(40)", true, true, rlB, 3)
    KTILE_BODY(18, "vmcnt(24)", true, true, rlA, 0)
    KTILE_BODY(19, "vmcnt(16)", true, true, rlA, 0)
    for (int t = 20; t < NT - 3; ++t)
      KTILE_BODY(t, "vmcnt(8)", true, true, rlA, 0)
  } else {
    for (int t = 0; t < NT - 3; ++t)
      KTILE_BODY(t, "vmcnt(8)", true, true, rlA, 0)
  }
  KTILE_BODY(NT - 3, "vmcnt(4)", false, true, rlA, 0)
  KTILE_BODY(NT - 2, "vmcnt(0)", false, true, rlA, 0)   // drains rec stores
  KTILE_BODY(NT - 1, "vmcnt(0)", false, false, rlA, 0)
#undef KTILE_BODY
#undef RECBLK

  // ---- epilogue: C/D layout col = lane&15, row = (lane>>4)*4 + v  [m89/m91]
#pragma unroll
  for (int i = 0; i < 8; ++i) {
#pragma unroll
    for (int j = 0; j < 4; ++j) {
      const int col = n0 + wn * 64 + j * 16 + l15;
      const float bv = bias[col];
#pragma unroll
      for (int v = 0; v < 4; ++v) {
        const int row = m0 + wm * 128 + i * 16 + (lane >> 4) * 4 + v;
        const size_t o = (size_t)row * D_DIM + col;
        const float val = acc[i][j][v] + bv;
        if (GATE) {
          const float g = 1.f / (1.f + expf(-val));
          Ybf[o] = __float2bfloat16(g * __bfloat162float(ssm[o]));
        } else {
          Yf[o] = val;
        }
      }
    }
  }
}

// ---------------------------------------------------------------- launch
extern "C" void kernel_launch(void* const* d_in, const int* in_sizes, int n_in,
                              void* d_out, int out_size, void* d_ws, size_t ws_size,
                              hipStream_t stream) {
  const float* x  = (const float*)d_in[0];
  const float* A  = (const float*)d_in[1];
  const float* Bp = (const float*)d_in[2];
  const float* Cp = (const float*)d_in[3];
  const float* gw = (const float*)d_in[4];
  const float* gb = (const float*)d_in[5];
  const float* ow = (const float*)d_in[6];
  const float* ob = (const float*)d_in[7];
  float* out = (float*)d_out;

  // workspace layout (bytes)
  const size_t NEED = 73400320;
  if (ws_size < NEED) {
    fprintf(stderr, "kernel_launch: ws_size %zu < needed %zu\n", ws_size, NEED);
    return;
  }
  char* ws = (char*)d_ws;
  bf16*  x16   = (bf16*)(ws);                   // 33,554,432 B : x cast to bf16
  bf16*  ssm16 = (bf16*)(ws + 33554432);        // 33,554,432 B : ssm, then y in-place
  bf16*  gw16  = (bf16*)(ws + 67108864);        //  2,097,152 B
  bf16*  ow16  = (bf16*)(ws + 69206016);        //  2,097,152 B
  float* hfin  = (float*)(ws + 71303168);       //  1,048,576 B
  float* hin   = (float*)(ws + 72351744);       //  1,048,576 B

  // pass1 + fused weight cast: 512 ssm blocks + 128 cast blocks
  ssm_pass1<<<B_DIM * NC * 2 + 128, 256, 0, stream>>>(
      x, A, Bp, hfin, (unsigned short*)x16, gw, ow,
      (unsigned short*)gw16, (unsigned short*)ow16);
  ssm_pass2<<<(B_DIM * D_DIM) / 256, 256, 0, stream>>>(A, hfin, hin);

  // gate GEMM with PIPELINED fused ssm recurrence, then
  // y = sigmoid(x@gw^T + gb) * ssm  (written in-place over ssm16)
  gemm256<true><<<GM * GN, 512, 0, stream>>>(
      x16, gw16, gb, ssm16, ssm16, nullptr,
      (const unsigned short*)x16, A, Bp, Cp, hin);
  // out GEMM: out = y@ow^T + ob  (fp32)
  gemm256<false><<<GM * GN, 512, 0, stream>>>(
      ssm16, ow16, ob, nullptr, nullptr, out,
      nullptr, nullptr, nullptr, nullptr, nullptr);
}